// Round 4
// baseline (2713.851 us; speedup 1.0000x reference)
//
#include <hip/hip_runtime.h>

// ============================================================================
// Attention_18923625906467 — MI355X (round 4)
//   out = ((x@Wsep^T)@Wmulti^T -> heads -> softmax(QK^T/sqrt(512))V) @ Wres^T
// B=2,S=2048,D=512,H=8.
//
// ROUND-3 DIAGNOSIS: inputs/outputs are FLOAT32 (reference is jnp.float32;
// the test label's "bf16" is hard-coded text). Rounds 1-3 read f32 buffers
// as bf16 -> bogus exponent bits -> NaN operands -> NaN output. Fix: convert
// inputs f32->bf16 once into d_ws, compute in bf16 MFMA (2% threshold),
// write f32 output.
// ============================================================================

typedef __bf16 bf16_t;
typedef __bf16 bf16x4 __attribute__((ext_vector_type(4)));
typedef __bf16 bf16x8 __attribute__((ext_vector_type(8)));
typedef float  f32x4  __attribute__((ext_vector_type(4)));

#define BM 128
#define BN 128
#define BK 64
#define LDK 72   // LDS row stride (bf16): 144B = 9*16B aligned, 2-way banks (free)

// ---------------------------------------------------------------------------
__global__ void f32_to_bf16(const float* __restrict__ src, bf16_t* __restrict__ dst, int n4)
{
    const int i = blockIdx.x * 256 + threadIdx.x;
    if (i < n4) {
        const float4 v = ((const float4*)src)[i];
        bf16x4 o;
        o[0] = (bf16_t)v.x; o[1] = (bf16_t)v.y; o[2] = (bf16_t)v.z; o[3] = (bf16_t)v.w;
        ((bf16x4*)dst)[i] = o;
    }
}

// ---------------------------------------------------------------------------
// GEMM: D = A @ W^T + bias.  A:[M,lda], W:[N,ldw] row-major bf16, K inner.
//   C    != nullptr : write bf16 C[row*N+col]
//   Cacc != nullptr : f32 Cacc[row*N+col] = v (accFirst) or += v
//   qk   != nullptr : attention scatter (col = hh*1536 + off, row = bb*2048+ss):
//       off<1024 -> qk[((bb*hmul+hh)*2048+ss)*1024 + off]   (Q:0..511 K:512..1023)
//       else     -> vT[((bb*hmul+hh)*512+(off-1024))*2048 + ss]
// ---------------------------------------------------------------------------
__global__ __launch_bounds__(256, 2)
void gemm_bt(const bf16_t* __restrict__ A, int lda,
             const bf16_t* __restrict__ W, int ldw,
             const float* __restrict__ bias,
             bf16_t* __restrict__ C, float* __restrict__ Cacc, int accFirst,
             int N, int K,
             bf16_t* __restrict__ qk, bf16_t* __restrict__ vT, int hmul)
{
    __shared__ __align__(16) bf16_t As[BM * LDK];
    __shared__ __align__(16) bf16_t Ws[BN * LDK];

    const int tid  = threadIdx.x;
    const int wave = tid >> 6;
    const int lane = tid & 63;
    const int quad = lane >> 4;
    const int l16  = lane & 15;
    const int bm = blockIdx.y * BM;
    const int bn = blockIdx.x * BN;
    const int wm = (wave >> 1) * 64;
    const int wn = (wave & 1) * 64;

    f32x4 acc[4][4] = {};

    const int srow = tid >> 3;   // 32 rows per pass, 8 x 16B segments per row
    const int sseg = tid & 7;

    for (int k0 = 0; k0 < K; k0 += BK) {
        #pragma unroll
        for (int it = 0; it < 4; ++it) {
            const int row = it * 32 + srow;
            const int4 va = *(const int4*)(A + (size_t)(bm + row) * lda + k0 + sseg * 8);
            *(int4*)(As + row * LDK + sseg * 8) = va;
            const int4 vw = *(const int4*)(W + (size_t)(bn + row) * ldw + k0 + sseg * 8);
            *(int4*)(Ws + row * LDK + sseg * 8) = vw;
        }
        __syncthreads();
        #pragma unroll
        for (int kk = 0; kk < BK; kk += 32) {
            bf16x8 af[4], wf[4];
            #pragma unroll
            for (int i = 0; i < 4; ++i)
                af[i] = *(const bf16x8*)(As + (wm + i * 16 + l16) * LDK + kk + quad * 8);
            #pragma unroll
            for (int j = 0; j < 4; ++j)
                wf[j] = *(const bf16x8*)(Ws + (wn + j * 16 + l16) * LDK + kk + quad * 8);
            #pragma unroll
            for (int i = 0; i < 4; ++i)
                #pragma unroll
                for (int j = 0; j < 4; ++j)
                    acc[i][j] = __builtin_amdgcn_mfma_f32_16x16x32_bf16(af[i], wf[j], acc[i][j], 0, 0, 0);
        }
        __syncthreads();
    }

    // C/D layout: col = l16, row = quad*4 + r within each 16x16 tile.
    #pragma unroll
    for (int j = 0; j < 4; ++j) {
        const int col = bn + wn + j * 16 + l16;
        const float bv = bias ? bias[col] : 0.f;
        #pragma unroll
        for (int i = 0; i < 4; ++i) {
            const int row0 = bm + wm + i * 16 + quad * 4;
            #pragma unroll
            for (int r = 0; r < 4; ++r) {
                const int row = row0 + r;
                const float v = acc[i][j][r] + bv;
                if (C)
                    C[(size_t)row * N + col] = (bf16_t)v;
                if (Cacc) {
                    const size_t idx = (size_t)row * N + col;
                    Cacc[idx] = accFirst ? v : (Cacc[idx] + v);
                }
                if (qk) {
                    const int hh  = col / 1536;
                    const int off = col - hh * 1536;
                    const int bb  = row >> 11;
                    const int ss  = row & 2047;
                    if (off < 1024)
                        qk[((size_t)((bb * hmul + hh) * 2048 + ss)) * 1024 + off] = (bf16_t)v;
                    else
                        vT[((size_t)((bb * hmul + hh) * 512 + (off - 1024))) * 2048 + ss] = (bf16_t)v;
                }
            }
        }
    }
}

// ---------------------------------------------------------------------------
// Flash attention. Grid (32, nH, nB). Block = 4 waves; wave owns 16 q-rows,
// O[16][512] f32 in registers. qk rows are [Q(512) | K(512)] per (b,h);
// vT is [512,2048] per (b,h). Online softmax in quad 16-lane groups.
// Output bf16: aout[((b*2048)+qrow)*out_stride + h_blk*coloff_per_head + d].
// ---------------------------------------------------------------------------
__global__ void attn(const bf16_t* __restrict__ qk, const bf16_t* __restrict__ vT,
                     bf16_t* __restrict__ aout, int hmul,
                     int out_stride, int coloff_per_head)
{
    __shared__ __align__(16) bf16_t Plds[4][16 * 72];

    const int tid  = threadIdx.x;
    const int wave = tid >> 6;
    const int lane = tid & 63;
    const int quad = lane >> 4;
    const int l16  = lane & 15;

    const int qt    = blockIdx.x;
    const int h_blk = blockIdx.y;
    const int b     = blockIdx.z;

    const int qbase = qt * 64 + wave * 16;
    const bf16_t* qp = qk + ((size_t)((b * hmul + h_blk) * 2048 + qbase)) * 1024;
    const bf16_t* kp = qk + ((size_t)((b * hmul + h_blk) * 2048)) * 1024 + 512;
    const bf16_t* vp = vT + (size_t)(b * hmul + h_blk) * 512 * 2048;

    f32x4 o[32] = {};
    float m_i[4], l_i[4];
    #pragma unroll
    for (int r = 0; r < 4; ++r) { m_i[r] = -10000.f; l_i[r] = 0.f; }

    const float scale = 0.0441941738241592f;  // 1/sqrt(512)

    for (int kt = 0; kt < 32; ++kt) {
        const int key0 = kt * 64;

        // ---- S = Q K^T (16 q-rows x 64 keys per wave) ----
        f32x4 s[4] = {};
        for (int ks = 0; ks < 16; ++ks) {
            const bf16x8 qf = *(const bf16x8*)(qp + (size_t)l16 * 1024 + ks * 32 + quad * 8);
            #pragma unroll
            for (int j = 0; j < 4; ++j) {
                const bf16x8 kf = *(const bf16x8*)(kp + (size_t)(key0 + j * 16 + l16) * 1024 + ks * 32 + quad * 8);
                s[j] = __builtin_amdgcn_mfma_f32_16x16x32_bf16(qf, kf, s[j], 0, 0, 0);
            }
        }
        #pragma unroll
        for (int j = 0; j < 4; ++j) s[j] *= scale;

        // ---- online softmax; q-row r spans the quad's 16 lanes ----
        float alpha[4];
        #pragma unroll
        for (int r = 0; r < 4; ++r) {
            float v = fmaxf(fmaxf(s[0][r], s[1][r]), fmaxf(s[2][r], s[3][r]));
            v = fmaxf(v, __shfl_xor(v, 1));
            v = fmaxf(v, __shfl_xor(v, 2));
            v = fmaxf(v, __shfl_xor(v, 4));
            v = fmaxf(v, __shfl_xor(v, 8));
            const float mn = fmaxf(m_i[r], v);
            alpha[r] = __expf(m_i[r] - mn);
            m_i[r] = mn;
        }
        #pragma unroll
        for (int r = 0; r < 4; ++r) {
            float t = 0.f;
            #pragma unroll
            for (int j = 0; j < 4; ++j) {
                const float p = __expf(s[j][r] - m_i[r]);
                s[j][r] = p;
                t += p;
            }
            t += __shfl_xor(t, 1);
            t += __shfl_xor(t, 2);
            t += __shfl_xor(t, 4);
            t += __shfl_xor(t, 8);
            l_i[r] = l_i[r] * alpha[r] + t;
        }
        #pragma unroll
        for (int jj = 0; jj < 32; ++jj) {
            f32x4 a4 = o[jj];
            a4[0] *= alpha[0]; a4[1] *= alpha[1];
            a4[2] *= alpha[2]; a4[3] *= alpha[3];
            o[jj] = a4;
        }

        // ---- P: C-layout regs -> LDS (bf16) -> A-layout fragments ----
        #pragma unroll
        for (int j = 0; j < 4; ++j)
            #pragma unroll
            for (int r = 0; r < 4; ++r)
                Plds[wave][(quad * 4 + r) * 72 + j * 16 + l16] = (bf16_t)s[j][r];
        __syncthreads();

        // ---- O += P V ----
        #pragma unroll
        for (int ks2 = 0; ks2 < 2; ++ks2) {
            const bf16x8 pf = *(const bf16x8*)(&Plds[wave][l16 * 72 + ks2 * 32 + quad * 8]);
            #pragma unroll
            for (int jj = 0; jj < 32; ++jj) {
                const bf16x8 vf = *(const bf16x8*)(vp + (size_t)(jj * 16 + l16) * 2048 + key0 + ks2 * 32 + quad * 8);
                o[jj] = __builtin_amdgcn_mfma_f32_16x16x32_bf16(pf, vf, o[jj], 0, 0, 0);
            }
        }
        __syncthreads();
    }

    // ---- epilogue ----
    float inv[4];
    #pragma unroll
    for (int r = 0; r < 4; ++r) inv[r] = 1.f / l_i[r];
    const int coloff = h_blk * coloff_per_head;
    #pragma unroll
    for (int jj = 0; jj < 32; ++jj) {
        const int d = jj * 16 + l16;
        #pragma unroll
        for (int r = 0; r < 4; ++r) {
            const int row = b * 2048 + qbase + quad * 4 + r;
            aout[(size_t)row * out_stride + coloff + d] = (bf16_t)(o[jj][r] * inv[r]);
        }
    }
}

// ---------------------------------------------------------------------------
extern "C" void kernel_launch(void* const* d_in, const int* in_sizes, int n_in,
                              void* d_out, int out_size, void* d_ws, size_t ws_size,
                              hipStream_t stream)
{
    const float* x       = (const float*)d_in[0];  // [4096, 512]   f32
    const float* W_sep   = (const float*)d_in[1];  // [1536, 512]   f32
    const float* b_sep   = (const float*)d_in[2];  // [1536]        f32
    const float* W_multi = (const float*)d_in[3];  // [12288, 1536] f32
    const float* b_multi = (const float*)d_in[4];  // [12288]       f32
    const float* W_res   = (const float*)d_in[5];  // [512, 4096]   f32
    const float* b_res   = (const float*)d_in[6];  // [512]         f32
    float* out = (float*)d_out;                    // [4096, 512]   f32

    char* ws = (char*)d_ws;
    const dim3 blk(256);

    if (ws_size >= 160956416ull) {
        // ------------- tier 1: 161 MB, whole-problem dispatches -------------
        bf16_t* wmb = (bf16_t*)(ws);                   // [12288,1536] 37.75 MB
        bf16_t* av  = (bf16_t*)(ws);                   // [4096,4096]  33.55 MB (over wmb, dead)
        bf16_t* xb  = (bf16_t*)(ws +  37748736ull);    // [4096,512]    4.19 MB
        bf16_t* wsb = (bf16_t*)(ws +  41943040ull);    // [1536,512]    1.57 MB
        bf16_t* wrb = (bf16_t*)(ws +  43515904ull);    // [512,4096]    4.19 MB
        bf16_t* h1  = (bf16_t*)(ws +  47710208ull);    // [4096,1536]  12.58 MB
        bf16_t* qk  = (bf16_t*)(ws +  60293120ull);    // [2,8,2048,1024] 67.11 MB
        bf16_t* vT  = (bf16_t*)(ws + 127401984ull);    // [2,8,512,2048]  33.55 MB

        f32_to_bf16<<<dim3( 2048), blk, 0, stream>>>(x,       xb,  2097152 / 4);
        f32_to_bf16<<<dim3(  768), blk, 0, stream>>>(W_sep,   wsb,  786432 / 4);
        f32_to_bf16<<<dim3(18432), blk, 0, stream>>>(W_multi, wmb, 18874368 / 4);
        f32_to_bf16<<<dim3( 2048), blk, 0, stream>>>(W_res,   wrb,  2097152 / 4);

        gemm_bt<<<dim3(12, 32), blk, 0, stream>>>(xb, 512, wsb, 512, b_sep,
                                                  h1, nullptr, 0, 1536, 512,
                                                  nullptr, nullptr, 0);
        gemm_bt<<<dim3(96, 32), blk, 0, stream>>>(h1, 1536, wmb, 1536, b_multi,
                                                  nullptr, nullptr, 0, 12288, 1536,
                                                  qk, vT, 8);
        attn<<<dim3(32, 8, 2), blk, 0, stream>>>(qk, vT, av, 8, 4096, 512);
        gemm_bt<<<dim3(4, 32), blk, 0, stream>>>(av, 4096, wrb, 4096, b_res,
                                                 nullptr, out, 1, 512, 4096,
                                                 nullptr, nullptr, 0);
    } else if (ws_size >= 39845888ull) {
        // ------------- tier 2: 39.8 MB, per-head streaming -------------
        bf16_t* h1    = (bf16_t*)(ws);                 // [4096,1536]  12.58 MB
        bf16_t* xb    = (bf16_t*)(ws + 12582912ull);   // [4096,512]    4.19 MB (dead after GEMM1)
        bf16_t* av_h  = (bf16_t*)(ws + 12582912ull);   //   reuse: [4096,512] bf16
        bf16_t* wsb   = (bf16_t*)(ws + 16777216ull);   // [1536,512]    1.57 MB
        bf16_t* wrb   = (bf16_t*)(ws + 18350080ull);   // [512,4096]    4.19 MB
        bf16_t* wmb_h = (bf16_t*)(ws + 22544384ull);   // [1536,1536]   4.72 MB
        bf16_t* qk_h  = (bf16_t*)(ws + 27262976ull);   // [2,2048,1024] 8.39 MB
        bf16_t* vT_h  = (bf16_t*)(ws + 35651584ull);   // [2,512,2048]  4.19 MB

        f32_to_bf16<<<dim3(2048), blk, 0, stream>>>(x,     xb,  2097152 / 4);
        f32_to_bf16<<<dim3( 768), blk, 0, stream>>>(W_sep, wsb,  786432 / 4);
        f32_to_bf16<<<dim3(2048), blk, 0, stream>>>(W_res, wrb,  2097152 / 4);

        gemm_bt<<<dim3(12, 32), blk, 0, stream>>>(xb, 512, wsb, 512, b_sep,
                                                  h1, nullptr, 0, 1536, 512,
                                                  nullptr, nullptr, 0);
        for (int h = 0; h < 8; ++h) {
            f32_to_bf16<<<dim3(2304), blk, 0, stream>>>(W_multi + (size_t)h * 1536 * 1536,
                                                        wmb_h, 2359296 / 4);
            gemm_bt<<<dim3(12, 32), blk, 0, stream>>>(h1, 1536, wmb_h, 1536,
                    b_multi + h * 1536, nullptr, nullptr, 0, 1536, 1536,
                    qk_h, vT_h, 1);
            attn<<<dim3(32, 1, 2), blk, 0, stream>>>(qk_h, vT_h, av_h, 1, 512, 0);
            gemm_bt<<<dim3(4, 32), blk, 0, stream>>>(av_h, 512, wrb + h * 512, 4096,
                    (h == 0) ? b_res : nullptr, nullptr, out, (h == 0) ? 1 : 0,
                    512, 512, nullptr, nullptr, 0);
        }
    } else {
        // ------------- tier 3: exactly 32 MiB, per-(batch,head) -------------
        bf16_t* h1    = (bf16_t*)(ws);                 // [4096,1536]  12.58 MB
        bf16_t* xb    = (bf16_t*)(ws + 12582912ull);   // [4096,512]    4.19 MB (dead after GEMM1)
        bf16_t* av_bh = (bf16_t*)(ws + 12582912ull);   //   reuse: [2048,512] bf16
        bf16_t* wsb   = (bf16_t*)(ws + 16777216ull);   // [1536,512]    1.57 MB
        bf16_t* wrb   = (bf16_t*)(ws + 18350080ull);   // [512,4096]    4.19 MB
        bf16_t* wmb_h = (bf16_t*)(ws + 22544384ull);   // [1536,1536]   4.72 MB
        bf16_t* qk_bh = (bf16_t*)(ws + 27262976ull);   // [2048,1024]   4.19 MB
        bf16_t* vT_bh = (bf16_t*)(ws + 31457280ull);   // [512,2048]    2.10 MB

        f32_to_bf16<<<dim3(2048), blk, 0, stream>>>(x,     xb,  2097152 / 4);
        f32_to_bf16<<<dim3( 768), blk, 0, stream>>>(W_sep, wsb,  786432 / 4);
        f32_to_bf16<<<dim3(2048), blk, 0, stream>>>(W_res, wrb,  2097152 / 4);

        gemm_bt<<<dim3(12, 32), blk, 0, stream>>>(xb, 512, wsb, 512, b_sep,
                                                  h1, nullptr, 0, 1536, 512,
                                                  nullptr, nullptr, 0);
        for (int h = 0; h < 8; ++h) {
            f32_to_bf16<<<dim3(2304), blk, 0, stream>>>(W_multi + (size_t)h * 1536 * 1536,
                                                        wmb_h, 2359296 / 4);
            for (int b = 0; b < 2; ++b) {
                gemm_bt<<<dim3(12, 16), blk, 0, stream>>>(h1 + (size_t)b * 2048 * 1536, 1536,
                        wmb_h, 1536, b_multi + h * 1536,
                        nullptr, nullptr, 0, 1536, 1536, qk_bh, vT_bh, 1);
                attn<<<dim3(32, 1, 1), blk, 0, stream>>>(qk_bh, vT_bh, av_bh, 1, 512, 0);
                gemm_bt<<<dim3(4, 16), blk, 0, stream>>>(av_bh, 512, wrb + h * 512, 4096,
                        (h == 0) ? b_res : nullptr, nullptr, out + (size_t)b * 2048 * 512,
                        (h == 0) ? 1 : 0, 512, 512, nullptr, nullptr, 0);
            }
        }
    }
}

// Round 5
// 1615.691 us; speedup vs baseline: 1.6797x; 1.6797x over previous
//
#include <hip/hip_runtime.h>

// ============================================================================
// Attention_18923625906467 — MI355X (round 5)
//   out = ((x@Wsep^T)@Wmulti^T -> heads -> softmax(QK^T/sqrt(512))V) @ Wres^T
// B=2,S=2048,D=512,H=8.  f32 in/out; bf16 MFMA compute (2%-rel threshold).
//
// R4 profile: attn = 84% of runtime, VGPR_Count=64 -> O-accumulator (128
// VGPRs) spilled to scratch (WRITE_SIZE 3.1 GB vs 33 MB output). Fix:
// __launch_bounds__(512,2) + 8-wave blocks (128 q-rows) to also halve K/V
// HBM re-reads (FETCH 2.35 GB -> ~1 GB structural).
// ============================================================================

typedef __bf16 bf16_t;
typedef __bf16 bf16x4 __attribute__((ext_vector_type(4)));
typedef __bf16 bf16x8 __attribute__((ext_vector_type(8)));
typedef float  f32x4  __attribute__((ext_vector_type(4)));

#define BM 128
#define BN 128
#define BK 64
#define LDK 72   // LDS row stride (bf16): 144B = 9*16B aligned, 2-way banks (free)

// ---------------------------------------------------------------------------
__global__ void f32_to_bf16(const float* __restrict__ src, bf16_t* __restrict__ dst, int n4)
{
    const int i = blockIdx.x * 256 + threadIdx.x;
    if (i < n4) {
        const float4 v = ((const float4*)src)[i];
        bf16x4 o;
        o[0] = (bf16_t)v.x; o[1] = (bf16_t)v.y; o[2] = (bf16_t)v.z; o[3] = (bf16_t)v.w;
        ((bf16x4*)dst)[i] = o;
    }
}

// ---------------------------------------------------------------------------
// GEMM: D = A @ W^T + bias.  A:[M,lda], W:[N,ldw] row-major bf16, K inner.
//   C    != nullptr : write bf16 C[row*N+col]
//   Cacc != nullptr : f32 Cacc[row*N+col] = v (accFirst) or += v
//   qk   != nullptr : attention scatter (col = hh*1536 + off, row = bb*2048+ss):
//       off<1024 -> qk[((bb*hmul+hh)*2048+ss)*1024 + off]   (Q:0..511 K:512..1023)
//       else     -> vT[((bb*hmul+hh)*512+(off-1024))*2048 + ss]
// ---------------------------------------------------------------------------
__global__ __launch_bounds__(256, 2)
void gemm_bt(const bf16_t* __restrict__ A, int lda,
             const bf16_t* __restrict__ W, int ldw,
             const float* __restrict__ bias,
             bf16_t* __restrict__ C, float* __restrict__ Cacc, int accFirst,
             int N, int K,
             bf16_t* __restrict__ qk, bf16_t* __restrict__ vT, int hmul)
{
    __shared__ __align__(16) bf16_t As[BM * LDK];
    __shared__ __align__(16) bf16_t Ws[BN * LDK];

    const int tid  = threadIdx.x;
    const int wave = tid >> 6;
    const int lane = tid & 63;
    const int quad = lane >> 4;
    const int l16  = lane & 15;
    const int bm = blockIdx.y * BM;
    const int bn = blockIdx.x * BN;
    const int wm = (wave >> 1) * 64;
    const int wn = (wave & 1) * 64;

    f32x4 acc[4][4] = {};

    const int srow = tid >> 3;   // 32 rows per pass, 8 x 16B segments per row
    const int sseg = tid & 7;

    for (int k0 = 0; k0 < K; k0 += BK) {
        #pragma unroll
        for (int it = 0; it < 4; ++it) {
            const int row = it * 32 + srow;
            const int4 va = *(const int4*)(A + (size_t)(bm + row) * lda + k0 + sseg * 8);
            *(int4*)(As + row * LDK + sseg * 8) = va;
            const int4 vw = *(const int4*)(W + (size_t)(bn + row) * ldw + k0 + sseg * 8);
            *(int4*)(Ws + row * LDK + sseg * 8) = vw;
        }
        __syncthreads();
        #pragma unroll
        for (int kk = 0; kk < BK; kk += 32) {
            bf16x8 af[4], wf[4];
            #pragma unroll
            for (int i = 0; i < 4; ++i)
                af[i] = *(const bf16x8*)(As + (wm + i * 16 + l16) * LDK + kk + quad * 8);
            #pragma unroll
            for (int j = 0; j < 4; ++j)
                wf[j] = *(const bf16x8*)(Ws + (wn + j * 16 + l16) * LDK + kk + quad * 8);
            #pragma unroll
            for (int i = 0; i < 4; ++i)
                #pragma unroll
                for (int j = 0; j < 4; ++j)
                    acc[i][j] = __builtin_amdgcn_mfma_f32_16x16x32_bf16(af[i], wf[j], acc[i][j], 0, 0, 0);
        }
        __syncthreads();
    }

    // C/D layout: col = l16, row = quad*4 + r within each 16x16 tile.
    #pragma unroll
    for (int j = 0; j < 4; ++j) {
        const int col = bn + wn + j * 16 + l16;
        const float bv = bias ? bias[col] : 0.f;
        #pragma unroll
        for (int i = 0; i < 4; ++i) {
            const int row0 = bm + wm + i * 16 + quad * 4;
            #pragma unroll
            for (int r = 0; r < 4; ++r) {
                const int row = row0 + r;
                const float v = acc[i][j][r] + bv;
                if (C)
                    C[(size_t)row * N + col] = (bf16_t)v;
                if (Cacc) {
                    const size_t idx = (size_t)row * N + col;
                    Cacc[idx] = accFirst ? v : (Cacc[idx] + v);
                }
                if (qk) {
                    const int hh  = col / 1536;
                    const int off = col - hh * 1536;
                    const int bb  = row >> 11;
                    const int ss  = row & 2047;
                    if (off < 1024)
                        qk[((size_t)((bb * hmul + hh) * 2048 + ss)) * 1024 + off] = (bf16_t)v;
                    else
                        vT[((size_t)((bb * hmul + hh) * 512 + (off - 1024))) * 2048 + ss] = (bf16_t)v;
                }
            }
        }
    }
}

// ---------------------------------------------------------------------------
// Flash attention. 1-D grid of nPairs*16 blocks; block = 8 waves (512 thr),
// 128 q-rows per block (16 per wave). O[16][512] f32 = 128 VGPRs per wave;
// __launch_bounds__(512,2) caps at 256 VGPR -> no spill (R4: VGPR_Count=64
// meant the accumulator lived in scratch -> 3.1 GB of spill writes).
// pair p = bid % nPairs (spreads pairs across XCDs for L2 reuse);
// qk rows are [Q(512)|K(512)] per pair; vT is [512,2048] per pair.
// Output: aout[((p/nH)*2048 + qrow)*out_stride + (p%nH)*coloff_per_head + d].
// ---------------------------------------------------------------------------
__global__ __launch_bounds__(512, 2)
void attn(const bf16_t* __restrict__ qk, const bf16_t* __restrict__ vT,
          bf16_t* __restrict__ aout, int nPairs, int nH,
          int out_stride, int coloff_per_head)
{
    __shared__ __align__(16) bf16_t Plds[8][16 * 72];

    const int tid  = threadIdx.x;
    const int wave = tid >> 6;
    const int lane = tid & 63;
    const int quad = lane >> 4;
    const int l16  = lane & 15;

    const int bid = blockIdx.x;
    const int p   = bid % nPairs;     // buffer pair (b*nH + h)
    const int qt  = bid / nPairs;     // 0..15, 128 rows each

    const int qbase = qt * 128 + wave * 16;
    const bf16_t* qp = qk + ((size_t)(p * 2048 + qbase)) * 1024;
    const bf16_t* kp = qk + ((size_t)(p * 2048)) * 1024 + 512;
    const bf16_t* vp = vT + (size_t)p * 512 * 2048;

    f32x4 o[32] = {};
    float m_i[4], l_i[4];
    #pragma unroll
    for (int r = 0; r < 4; ++r) { m_i[r] = -10000.f; l_i[r] = 0.f; }

    const float scale = 0.0441941738241592f;  // 1/sqrt(512)

    for (int kt = 0; kt < 32; ++kt) {
        const int key0 = kt * 64;

        // ---- S = Q K^T (16 q-rows x 64 keys per wave) ----
        f32x4 s[4] = {};
        for (int ks = 0; ks < 16; ++ks) {
            const bf16x8 qf = *(const bf16x8*)(qp + (size_t)l16 * 1024 + ks * 32 + quad * 8);
            #pragma unroll
            for (int j = 0; j < 4; ++j) {
                const bf16x8 kf = *(const bf16x8*)(kp + (size_t)(key0 + j * 16 + l16) * 1024 + ks * 32 + quad * 8);
                s[j] = __builtin_amdgcn_mfma_f32_16x16x32_bf16(qf, kf, s[j], 0, 0, 0);
            }
        }
        #pragma unroll
        for (int j = 0; j < 4; ++j) s[j] *= scale;

        // ---- online softmax; q-row r spans the quad's 16 lanes ----
        float alpha[4];
        #pragma unroll
        for (int r = 0; r < 4; ++r) {
            float v = fmaxf(fmaxf(s[0][r], s[1][r]), fmaxf(s[2][r], s[3][r]));
            v = fmaxf(v, __shfl_xor(v, 1));
            v = fmaxf(v, __shfl_xor(v, 2));
            v = fmaxf(v, __shfl_xor(v, 4));
            v = fmaxf(v, __shfl_xor(v, 8));
            const float mn = fmaxf(m_i[r], v);
            alpha[r] = __expf(m_i[r] - mn);
            m_i[r] = mn;
        }
        #pragma unroll
        for (int r = 0; r < 4; ++r) {
            float t = 0.f;
            #pragma unroll
            for (int j = 0; j < 4; ++j) {
                const float pp = __expf(s[j][r] - m_i[r]);
                s[j][r] = pp;
                t += pp;
            }
            t += __shfl_xor(t, 1);
            t += __shfl_xor(t, 2);
            t += __shfl_xor(t, 4);
            t += __shfl_xor(t, 8);
            l_i[r] = l_i[r] * alpha[r] + t;
        }
        #pragma unroll
        for (int jj = 0; jj < 32; ++jj) {
            f32x4 a4 = o[jj];
            a4[0] *= alpha[0]; a4[1] *= alpha[1];
            a4[2] *= alpha[2]; a4[3] *= alpha[3];
            o[jj] = a4;
        }

        // ---- P: C-layout regs -> LDS (bf16) -> A-layout fragments ----
        // Wave-private buffer; same-wave DS ordering makes this safe w/o barrier.
        #pragma unroll
        for (int j = 0; j < 4; ++j)
            #pragma unroll
            for (int r = 0; r < 4; ++r)
                Plds[wave][(quad * 4 + r) * 72 + j * 16 + l16] = (bf16_t)s[j][r];

        // ---- O += P V ----
        #pragma unroll
        for (int ks2 = 0; ks2 < 2; ++ks2) {
            const bf16x8 pf = *(const bf16x8*)(&Plds[wave][l16 * 72 + ks2 * 32 + quad * 8]);
            #pragma unroll
            for (int jj = 0; jj < 32; ++jj) {
                const bf16x8 vf = *(const bf16x8*)(vp + (size_t)(jj * 16 + l16) * 2048 + key0 + ks2 * 32 + quad * 8);
                o[jj] = __builtin_amdgcn_mfma_f32_16x16x32_bf16(pf, vf, o[jj], 0, 0, 0);
            }
        }
    }

    // ---- epilogue ----
    float inv[4];
    #pragma unroll
    for (int r = 0; r < 4; ++r) inv[r] = 1.f / l_i[r];
    const int b_out  = p / nH;
    const int coloff = (p % nH) * coloff_per_head;
    #pragma unroll
    for (int jj = 0; jj < 32; ++jj) {
        const int d = jj * 16 + l16;
        #pragma unroll
        for (int r = 0; r < 4; ++r) {
            const int row = b_out * 2048 + qbase + quad * 4 + r;
            aout[(size_t)row * out_stride + coloff + d] = (bf16_t)(o[jj][r] * inv[r]);
        }
    }
}

// ---------------------------------------------------------------------------
extern "C" void kernel_launch(void* const* d_in, const int* in_sizes, int n_in,
                              void* d_out, int out_size, void* d_ws, size_t ws_size,
                              hipStream_t stream)
{
    const float* x       = (const float*)d_in[0];  // [4096, 512]   f32
    const float* W_sep   = (const float*)d_in[1];  // [1536, 512]   f32
    const float* b_sep   = (const float*)d_in[2];  // [1536]        f32
    const float* W_multi = (const float*)d_in[3];  // [12288, 1536] f32
    const float* b_multi = (const float*)d_in[4];  // [12288]       f32
    const float* W_res   = (const float*)d_in[5];  // [512, 4096]   f32
    const float* b_res   = (const float*)d_in[6];  // [512]         f32
    float* out = (float*)d_out;                    // [4096, 512]   f32

    char* ws = (char*)d_ws;
    const dim3 blk(256);

    if (ws_size >= 160956416ull) {
        // ------------- tier 1: 161 MB, whole-problem dispatches -------------
        bf16_t* wmb = (bf16_t*)(ws);                   // [12288,1536] 37.75 MB
        bf16_t* av  = (bf16_t*)(ws);                   // [4096,4096]  33.55 MB (over wmb, dead)
        bf16_t* xb  = (bf16_t*)(ws +  37748736ull);    // [4096,512]    4.19 MB
        bf16_t* wsb = (bf16_t*)(ws +  41943040ull);    // [1536,512]    1.57 MB
        bf16_t* wrb = (bf16_t*)(ws +  43515904ull);    // [512,4096]    4.19 MB
        bf16_t* h1  = (bf16_t*)(ws +  47710208ull);    // [4096,1536]  12.58 MB
        bf16_t* qk  = (bf16_t*)(ws +  60293120ull);    // [2,8,2048,1024] 67.11 MB
        bf16_t* vT  = (bf16_t*)(ws + 127401984ull);    // [2,8,512,2048]  33.55 MB

        f32_to_bf16<<<dim3( 2048), blk, 0, stream>>>(x,       xb,  2097152 / 4);
        f32_to_bf16<<<dim3(  768), blk, 0, stream>>>(W_sep,   wsb,  786432 / 4);
        f32_to_bf16<<<dim3(18432), blk, 0, stream>>>(W_multi, wmb, 18874368 / 4);
        f32_to_bf16<<<dim3( 2048), blk, 0, stream>>>(W_res,   wrb,  2097152 / 4);

        gemm_bt<<<dim3(12, 32), blk, 0, stream>>>(xb, 512, wsb, 512, b_sep,
                                                  h1, nullptr, 0, 1536, 512,
                                                  nullptr, nullptr, 0);
        gemm_bt<<<dim3(96, 32), blk, 0, stream>>>(h1, 1536, wmb, 1536, b_multi,
                                                  nullptr, nullptr, 0, 12288, 1536,
                                                  qk, vT, 8);
        attn<<<dim3(256), dim3(512), 0, stream>>>(qk, vT, av, 16, 8, 4096, 512);
        gemm_bt<<<dim3(4, 32), blk, 0, stream>>>(av, 4096, wrb, 4096, b_res,
                                                 nullptr, out, 1, 512, 4096,
                                                 nullptr, nullptr, 0);
    } else if (ws_size >= 39845888ull) {
        // ------------- tier 2: 39.8 MB, per-head streaming -------------
        bf16_t* h1    = (bf16_t*)(ws);                 // [4096,1536]  12.58 MB
        bf16_t* xb    = (bf16_t*)(ws + 12582912ull);   // [4096,512]    4.19 MB (dead after GEMM1)
        bf16_t* av_h  = (bf16_t*)(ws + 12582912ull);   //   reuse: [4096,512] bf16
        bf16_t* wsb   = (bf16_t*)(ws + 16777216ull);   // [1536,512]    1.57 MB
        bf16_t* wrb   = (bf16_t*)(ws + 18350080ull);   // [512,4096]    4.19 MB
        bf16_t* wmb_h = (bf16_t*)(ws + 22544384ull);   // [1536,1536]   4.72 MB
        bf16_t* qk_h  = (bf16_t*)(ws + 27262976ull);   // [2,2048,1024] 8.39 MB
        bf16_t* vT_h  = (bf16_t*)(ws + 35651584ull);   // [2,512,2048]  4.19 MB

        f32_to_bf16<<<dim3(2048), blk, 0, stream>>>(x,     xb,  2097152 / 4);
        f32_to_bf16<<<dim3( 768), blk, 0, stream>>>(W_sep, wsb,  786432 / 4);
        f32_to_bf16<<<dim3(2048), blk, 0, stream>>>(W_res, wrb,  2097152 / 4);

        gemm_bt<<<dim3(12, 32), blk, 0, stream>>>(xb, 512, wsb, 512, b_sep,
                                                  h1, nullptr, 0, 1536, 512,
                                                  nullptr, nullptr, 0);
        for (int h = 0; h < 8; ++h) {
            f32_to_bf16<<<dim3(2304), blk, 0, stream>>>(W_multi + (size_t)h * 1536 * 1536,
                                                        wmb_h, 2359296 / 4);
            gemm_bt<<<dim3(12, 32), blk, 0, stream>>>(h1, 1536, wmb_h, 1536,
                    b_multi + h * 1536, nullptr, nullptr, 0, 1536, 1536,
                    qk_h, vT_h, 1);
            attn<<<dim3(32), dim3(512), 0, stream>>>(qk_h, vT_h, av_h, 2, 1, 512, 0);
            gemm_bt<<<dim3(4, 32), blk, 0, stream>>>(av_h, 512, wrb + h * 512, 4096,
                    (h == 0) ? b_res : nullptr, nullptr, out, (h == 0) ? 1 : 0,
                    512, 512, nullptr, nullptr, 0);
        }
    } else {
        // ------------- tier 3: exactly 32 MiB, per-(batch,head) -------------
        bf16_t* h1    = (bf16_t*)(ws);                 // [4096,1536]  12.58 MB
        bf16_t* xb    = (bf16_t*)(ws + 12582912ull);   // [4096,512]    4.19 MB (dead after GEMM1)
        bf16_t* av_bh = (bf16_t*)(ws + 12582912ull);   //   reuse: [2048,512] bf16
        bf16_t* wsb   = (bf16_t*)(ws + 16777216ull);   // [1536,512]    1.57 MB
        bf16_t* wrb   = (bf16_t*)(ws + 18350080ull);   // [512,4096]    4.19 MB
        bf16_t* wmb_h = (bf16_t*)(ws + 22544384ull);   // [1536,1536]   4.72 MB
        bf16_t* qk_bh = (bf16_t*)(ws + 27262976ull);   // [2048,1024]   4.19 MB
        bf16_t* vT_bh = (bf16_t*)(ws + 31457280ull);   // [512,2048]    2.10 MB

        f32_to_bf16<<<dim3(2048), blk, 0, stream>>>(x,     xb,  2097152 / 4);
        f32_to_bf16<<<dim3( 768), blk, 0, stream>>>(W_sep, wsb,  786432 / 4);
        f32_to_bf16<<<dim3(2048), blk, 0, stream>>>(W_res, wrb,  2097152 / 4);

        gemm_bt<<<dim3(12, 32), blk, 0, stream>>>(xb, 512, wsb, 512, b_sep,
                                                  h1, nullptr, 0, 1536, 512,
                                                  nullptr, nullptr, 0);
        for (int h = 0; h < 8; ++h) {
            f32_to_bf16<<<dim3(2304), blk, 0, stream>>>(W_multi + (size_t)h * 1536 * 1536,
                                                        wmb_h, 2359296 / 4);
            for (int b = 0; b < 2; ++b) {
                gemm_bt<<<dim3(12, 16), blk, 0, stream>>>(h1 + (size_t)b * 2048 * 1536, 1536,
                        wmb_h, 1536, b_multi + h * 1536,
                        nullptr, nullptr, 0, 1536, 1536, qk_bh, vT_bh, 1);
                attn<<<dim3(16), dim3(512), 0, stream>>>(qk_bh, vT_bh, av_bh, 1, 1, 512, 0);
                gemm_bt<<<dim3(4, 16), blk, 0, stream>>>(av_bh, 512, wrb + h * 512, 4096,
                        (h == 0) ? b_res : nullptr, nullptr, out + (size_t)b * 2048 * 512,
                        (h == 0) ? 1 : 0, 512, 512, nullptr, nullptr, 0);
            }
        }
    }
}

// Round 6
// 1038.601 us; speedup vs baseline: 2.6130x; 1.5556x over previous
//
#include <hip/hip_runtime.h>

// ============================================================================
// Attention_18923625906467 — MI355X (round 6)
//   out = ((x@Wsep^T)@Wmulti^T -> heads -> softmax(QK^T/sqrt(512))V) @ Wres^T
// B=2,S=2048,D=512,H=8.  f32 in/out; bf16 MFMA compute (2%-rel threshold).
//
// R5 profile: attn latency-bound (MfmaUtil 4.7%, HBM 12%, occ 24%) — per-MFMA
// global gathers for K/V + residual spill (WRITE 365 MB vs 33.5 MB output).
// R6: V-tile (32 keys) staged to LDS via async global_load_lds shared by all
// 8 waves, pipelined under QK; Q preloaded to registers once; unpadded
// stride-32 LDS (balanced banks for b128; satisfies global_load_lds's
// wave-uniform+lane*16 dest rule).
// ============================================================================

typedef __bf16 bf16_t;
typedef __bf16 bf16x4 __attribute__((ext_vector_type(4)));
typedef __bf16 bf16x8 __attribute__((ext_vector_type(8)));
typedef float  f32x4  __attribute__((ext_vector_type(4)));

#define BM 128
#define BN 128
#define BK 64
#define LDK 72   // GEMM LDS row stride (bf16): 144B = 9*16B aligned, 2-way banks

typedef const __attribute__((address_space(1))) void gvoid_t;
typedef __attribute__((address_space(3))) void svoid_t;

__device__ __forceinline__ void async_cp16(const bf16_t* g, bf16_t* l)
{
    __builtin_amdgcn_global_load_lds((gvoid_t*)g, (svoid_t*)l, 16, 0, 0);
}

// ---------------------------------------------------------------------------
__global__ void f32_to_bf16(const float* __restrict__ src, bf16_t* __restrict__ dst, int n4)
{
    const int i = blockIdx.x * 256 + threadIdx.x;
    if (i < n4) {
        const float4 v = ((const float4*)src)[i];
        bf16x4 o;
        o[0] = (bf16_t)v.x; o[1] = (bf16_t)v.y; o[2] = (bf16_t)v.z; o[3] = (bf16_t)v.w;
        ((bf16x4*)dst)[i] = o;
    }
}

// ---------------------------------------------------------------------------
// GEMM: D = A @ W^T + bias.  A:[M,lda], W:[N,ldw] row-major bf16, K inner.
//   C    != nullptr : write bf16 C[row*N+col]
//   Cacc != nullptr : f32 Cacc[row*N+col] = v (accFirst) or += v
//   qk   != nullptr : attention scatter (col = hh*1536 + off, row = bb*2048+ss):
//       off<1024 -> qk[((bb*hmul+hh)*2048+ss)*1024 + off]   (Q:0..511 K:512..1023)
//       else     -> vT[((bb*hmul+hh)*512+(off-1024))*2048 + ss]
// ---------------------------------------------------------------------------
__global__ __launch_bounds__(256, 2)
void gemm_bt(const bf16_t* __restrict__ A, int lda,
             const bf16_t* __restrict__ W, int ldw,
             const float* __restrict__ bias,
             bf16_t* __restrict__ C, float* __restrict__ Cacc, int accFirst,
             int N, int K,
             bf16_t* __restrict__ qk, bf16_t* __restrict__ vT, int hmul)
{
    __shared__ __align__(16) bf16_t As[BM * LDK];
    __shared__ __align__(16) bf16_t Ws[BN * LDK];

    const int tid  = threadIdx.x;
    const int wave = tid >> 6;
    const int lane = tid & 63;
    const int quad = lane >> 4;
    const int l16  = lane & 15;
    const int bm = blockIdx.y * BM;
    const int bn = blockIdx.x * BN;
    const int wm = (wave >> 1) * 64;
    const int wn = (wave & 1) * 64;

    f32x4 acc[4][4] = {};

    const int srow = tid >> 3;
    const int sseg = tid & 7;

    for (int k0 = 0; k0 < K; k0 += BK) {
        #pragma unroll
        for (int it = 0; it < 4; ++it) {
            const int row = it * 32 + srow;
            const int4 va = *(const int4*)(A + (size_t)(bm + row) * lda + k0 + sseg * 8);
            *(int4*)(As + row * LDK + sseg * 8) = va;
            const int4 vw = *(const int4*)(W + (size_t)(bn + row) * ldw + k0 + sseg * 8);
            *(int4*)(Ws + row * LDK + sseg * 8) = vw;
        }
        __syncthreads();
        #pragma unroll
        for (int kk = 0; kk < BK; kk += 32) {
            bf16x8 af[4], wf[4];
            #pragma unroll
            for (int i = 0; i < 4; ++i)
                af[i] = *(const bf16x8*)(As + (wm + i * 16 + l16) * LDK + kk + quad * 8);
            #pragma unroll
            for (int j = 0; j < 4; ++j)
                wf[j] = *(const bf16x8*)(Ws + (wn + j * 16 + l16) * LDK + kk + quad * 8);
            #pragma unroll
            for (int i = 0; i < 4; ++i)
                #pragma unroll
                for (int j = 0; j < 4; ++j)
                    acc[i][j] = __builtin_amdgcn_mfma_f32_16x16x32_bf16(af[i], wf[j], acc[i][j], 0, 0, 0);
        }
        __syncthreads();
    }

    #pragma unroll
    for (int j = 0; j < 4; ++j) {
        const int col = bn + wn + j * 16 + l16;
        const float bv = bias ? bias[col] : 0.f;
        #pragma unroll
        for (int i = 0; i < 4; ++i) {
            const int row0 = bm + wm + i * 16 + quad * 4;
            #pragma unroll
            for (int r = 0; r < 4; ++r) {
                const int row = row0 + r;
                const float v = acc[i][j][r] + bv;
                if (C)
                    C[(size_t)row * N + col] = (bf16_t)v;
                if (Cacc) {
                    const size_t idx = (size_t)row * N + col;
                    Cacc[idx] = accFirst ? v : (Cacc[idx] + v);
                }
                if (qk) {
                    const int hh  = col / 1536;
                    const int off = col - hh * 1536;
                    const int bb  = row >> 11;
                    const int ss  = row & 2047;
                    if (off < 1024)
                        qk[((size_t)((bb * hmul + hh) * 2048 + ss)) * 1024 + off] = (bf16_t)v;
                    else
                        vT[((size_t)((bb * hmul + hh) * 512 + (off - 1024))) * 2048 + ss] = (bf16_t)v;
                }
            }
        }
    }
}

// ---------------------------------------------------------------------------
// Flash attention, round-6 structure.
// Grid nPairs*16 blocks x 512 thr (8 waves, 128 q-rows/block, 16 per wave).
// KT=32 keys per step, 64 steps. Per step:
//   [async V-tile loads for this step already in flight]
//   QK from global K + preloaded Q regs -> softmax -> P to wave-private LDS
//   __syncthreads (drains vmcnt -> V tile ready)
//   PV from LDS V tile (shared by all 8 waves)
//   __syncthreads -> issue async V loads for next step
// LDS: Vs 512x32 (32 KB, unpadded: stride 64B balances b128 banks; required
// contiguous for global_load_lds), Plds 8x16x32 (8 KB).
// ---------------------------------------------------------------------------
__global__ __launch_bounds__(512, 2)
void attn(const bf16_t* __restrict__ qk, const bf16_t* __restrict__ vT,
          bf16_t* __restrict__ aout, int nPairs, int nH,
          int out_stride, int coloff_per_head)
{
    __shared__ __align__(16) bf16_t Vs[512 * 32];
    __shared__ __align__(16) bf16_t Plds[8][16 * 32];

    const int tid  = threadIdx.x;
    const int wave = tid >> 6;
    const int lane = tid & 63;
    const int quad = lane >> 4;
    const int l16  = lane & 15;

    const int bid = blockIdx.x;
    const int p   = bid % nPairs;     // pair (b*nH + h); same pair -> same XCD
    const int qt  = bid / nPairs;     // 0..15

    const int qbase = qt * 128 + wave * 16;
    const bf16_t* qp = qk + ((size_t)(p * 2048 + qbase)) * 1024;
    const bf16_t* kp = qk + ((size_t)(p * 2048)) * 1024 + 512;
    const bf16_t* vp = vT + (size_t)p * 512 * 2048;

    // V staging mapping: thread t, pass pp: row = pp*128 + (t>>2), seg = t&3.
    // LDS byte = pp*8192 + t*16  (contiguous per wave: uniform base + lane*16).
    const int vrow = tid >> 2;
    const int vseg = (tid & 3) * 8;

    // ---- preload Q fragments (read exactly once) ----
    bf16x8 qreg[16];
    #pragma unroll
    for (int ks = 0; ks < 16; ++ks)
        qreg[ks] = *(const bf16x8*)(qp + (size_t)l16 * 1024 + ks * 32 + quad * 8);

    f32x4 o[32] = {};
    float m_i[4], l_i[4];
    #pragma unroll
    for (int r = 0; r < 4; ++r) { m_i[r] = -10000.f; l_i[r] = 0.f; }

    const float scale = 0.0441941738241592f;  // 1/sqrt(512)

    // ---- stage tile 0 (async) ----
    #pragma unroll
    for (int pp = 0; pp < 4; ++pp)
        async_cp16(vp + (size_t)(pp * 128 + vrow) * 2048 + vseg,
                   Vs + (size_t)(pp * 128 + vrow) * 32 + vseg);

    for (int kt = 0; kt < 64; ++kt) {
        const int key0 = kt * 32;

        // ---- S = Q K^T (16 q-rows x 32 keys per wave), K from global ----
        f32x4 s[2] = {};
        #pragma unroll
        for (int ks = 0; ks < 16; ++ks) {
            #pragma unroll
            for (int j = 0; j < 2; ++j) {
                const bf16x8 kf = *(const bf16x8*)(kp + (size_t)(key0 + j * 16 + l16) * 1024 + ks * 32 + quad * 8);
                s[j] = __builtin_amdgcn_mfma_f32_16x16x32_bf16(qreg[ks], kf, s[j], 0, 0, 0);
            }
        }
        s[0] *= scale; s[1] *= scale;

        // ---- online softmax; q-row r spans the quad's 16 lanes ----
        float alpha[4];
        #pragma unroll
        for (int r = 0; r < 4; ++r) {
            float v = fmaxf(s[0][r], s[1][r]);
            v = fmaxf(v, __shfl_xor(v, 1));
            v = fmaxf(v, __shfl_xor(v, 2));
            v = fmaxf(v, __shfl_xor(v, 4));
            v = fmaxf(v, __shfl_xor(v, 8));
            const float mn = fmaxf(m_i[r], v);
            alpha[r] = __expf(m_i[r] - mn);
            m_i[r] = mn;
        }
        #pragma unroll
        for (int r = 0; r < 4; ++r) {
            float t = 0.f;
            #pragma unroll
            for (int j = 0; j < 2; ++j) {
                const float pe = __expf(s[j][r] - m_i[r]);
                s[j][r] = pe;
                t += pe;
            }
            t += __shfl_xor(t, 1);
            t += __shfl_xor(t, 2);
            t += __shfl_xor(t, 4);
            t += __shfl_xor(t, 8);
            l_i[r] = l_i[r] * alpha[r] + t;
        }
        #pragma unroll
        for (int jj = 0; jj < 32; ++jj) {
            f32x4 a4 = o[jj];
            a4[0] *= alpha[0]; a4[1] *= alpha[1];
            a4[2] *= alpha[2]; a4[3] *= alpha[3];
            o[jj] = a4;
        }

        // ---- P: C-layout regs -> wave-private LDS (A-layout source) ----
        #pragma unroll
        for (int j = 0; j < 2; ++j)
            #pragma unroll
            for (int r = 0; r < 4; ++r)
                Plds[wave][(quad * 4 + r) * 32 + j * 16 + l16] = (bf16_t)s[j][r];

        __syncthreads();   // drains vmcnt -> V tile(kt) resident in Vs

        // ---- O += P V from LDS ----
        const bf16x8 pf = *(const bf16x8*)(&Plds[wave][l16 * 32 + quad * 8]);
        #pragma unroll
        for (int jj = 0; jj < 32; ++jj) {
            const bf16x8 vf = *(const bf16x8*)(&Vs[(jj * 16 + l16) * 32 + quad * 8]);
            o[jj] = __builtin_amdgcn_mfma_f32_16x16x32_bf16(pf, vf, o[jj], 0, 0, 0);
        }

        __syncthreads();   // all waves done reading Vs(kt)

        if (kt + 1 < 64) {
            const int nk = key0 + 32;
            #pragma unroll
            for (int pp = 0; pp < 4; ++pp)
                async_cp16(vp + (size_t)(pp * 128 + vrow) * 2048 + nk + vseg,
                           Vs + (size_t)(pp * 128 + vrow) * 32 + vseg);
        }
    }

    // ---- epilogue ----
    float inv[4];
    #pragma unroll
    for (int r = 0; r < 4; ++r) inv[r] = 1.f / l_i[r];
    const int b_out  = p / nH;
    const int coloff = (p % nH) * coloff_per_head;
    #pragma unroll
    for (int jj = 0; jj < 32; ++jj) {
        const int d = jj * 16 + l16;
        #pragma unroll
        for (int r = 0; r < 4; ++r) {
            const int row = b_out * 2048 + qbase + quad * 4 + r;
            aout[(size_t)row * out_stride + coloff + d] = (bf16_t)(o[jj][r] * inv[r]);
        }
    }
}

// ---------------------------------------------------------------------------
extern "C" void kernel_launch(void* const* d_in, const int* in_sizes, int n_in,
                              void* d_out, int out_size, void* d_ws, size_t ws_size,
                              hipStream_t stream)
{
    const float* x       = (const float*)d_in[0];  // [4096, 512]   f32
    const float* W_sep   = (const float*)d_in[1];  // [1536, 512]   f32
    const float* b_sep   = (const float*)d_in[2];  // [1536]        f32
    const float* W_multi = (const float*)d_in[3];  // [12288, 1536] f32
    const float* b_multi = (const float*)d_in[4];  // [12288]       f32
    const float* W_res   = (const float*)d_in[5];  // [512, 4096]   f32
    const float* b_res   = (const float*)d_in[6];  // [512]         f32
    float* out = (float*)d_out;                    // [4096, 512]   f32

    char* ws = (char*)d_ws;
    const dim3 blk(256);

    if (ws_size >= 160956416ull) {
        // ------------- tier 1: 161 MB, whole-problem dispatches -------------
        bf16_t* wmb = (bf16_t*)(ws);                   // [12288,1536] 37.75 MB
        bf16_t* av  = (bf16_t*)(ws);                   // [4096,4096]  33.55 MB (over wmb, dead)
        bf16_t* xb  = (bf16_t*)(ws +  37748736ull);    // [4096,512]    4.19 MB
        bf16_t* wsb = (bf16_t*)(ws +  41943040ull);    // [1536,512]    1.57 MB
        bf16_t* wrb = (bf16_t*)(ws +  43515904ull);    // [512,4096]    4.19 MB
        bf16_t* h1  = (bf16_t*)(ws +  47710208ull);    // [4096,1536]  12.58 MB
        bf16_t* qk  = (bf16_t*)(ws +  60293120ull);    // [2,8,2048,1024] 67.11 MB
        bf16_t* vT  = (bf16_t*)(ws + 127401984ull);    // [2,8,512,2048]  33.55 MB

        f32_to_bf16<<<dim3( 2048), blk, 0, stream>>>(x,       xb,  2097152 / 4);
        f32_to_bf16<<<dim3(  768), blk, 0, stream>>>(W_sep,   wsb,  786432 / 4);
        f32_to_bf16<<<dim3(18432), blk, 0, stream>>>(W_multi, wmb, 18874368 / 4);
        f32_to_bf16<<<dim3( 2048), blk, 0, stream>>>(W_res,   wrb,  2097152 / 4);

        gemm_bt<<<dim3(12, 32), blk, 0, stream>>>(xb, 512, wsb, 512, b_sep,
                                                  h1, nullptr, 0, 1536, 512,
                                                  nullptr, nullptr, 0);
        gemm_bt<<<dim3(96, 32), blk, 0, stream>>>(h1, 1536, wmb, 1536, b_multi,
                                                  nullptr, nullptr, 0, 12288, 1536,
                                                  qk, vT, 8);
        attn<<<dim3(256), dim3(512), 0, stream>>>(qk, vT, av, 16, 8, 4096, 512);
        gemm_bt<<<dim3(4, 32), blk, 0, stream>>>(av, 4096, wrb, 4096, b_res,
                                                 nullptr, out, 1, 512, 4096,
                                                 nullptr, nullptr, 0);
    } else if (ws_size >= 39845888ull) {
        // ------------- tier 2: 39.8 MB, per-head streaming -------------
        bf16_t* h1    = (bf16_t*)(ws);                 // [4096,1536]  12.58 MB
        bf16_t* xb    = (bf16_t*)(ws + 12582912ull);   // [4096,512]    4.19 MB (dead after GEMM1)
        bf16_t* av_h  = (bf16_t*)(ws + 12582912ull);   //   reuse: [4096,512] bf16
        bf16_t* wsb   = (bf16_t*)(ws + 16777216ull);   // [1536,512]    1.57 MB
        bf16_t* wrb   = (bf16_t*)(ws + 18350080ull);   // [512,4096]    4.19 MB
        bf16_t* wmb_h = (bf16_t*)(ws + 22544384ull);   // [1536,1536]   4.72 MB
        bf16_t* qk_h  = (bf16_t*)(ws + 27262976ull);   // [2,2048,1024] 8.39 MB
        bf16_t* vT_h  = (bf16_t*)(ws + 35651584ull);   // [2,512,2048]  4.19 MB

        f32_to_bf16<<<dim3(2048), blk, 0, stream>>>(x,     xb,  2097152 / 4);
        f32_to_bf16<<<dim3( 768), blk, 0, stream>>>(W_sep, wsb,  786432 / 4);
        f32_to_bf16<<<dim3(2048), blk, 0, stream>>>(W_res, wrb,  2097152 / 4);

        gemm_bt<<<dim3(12, 32), blk, 0, stream>>>(xb, 512, wsb, 512, b_sep,
                                                  h1, nullptr, 0, 1536, 512,
                                                  nullptr, nullptr, 0);
        for (int h = 0; h < 8; ++h) {
            f32_to_bf16<<<dim3(2304), blk, 0, stream>>>(W_multi + (size_t)h * 1536 * 1536,
                                                        wmb_h, 2359296 / 4);
            gemm_bt<<<dim3(12, 32), blk, 0, stream>>>(h1, 1536, wmb_h, 1536,
                    b_multi + h * 1536, nullptr, nullptr, 0, 1536, 1536,
                    qk_h, vT_h, 1);
            attn<<<dim3(32), dim3(512), 0, stream>>>(qk_h, vT_h, av_h, 2, 1, 512, 0);
            gemm_bt<<<dim3(4, 32), blk, 0, stream>>>(av_h, 512, wrb + h * 512, 4096,
                    (h == 0) ? b_res : nullptr, nullptr, out, (h == 0) ? 1 : 0,
                    512, 512, nullptr, nullptr, 0);
        }
    } else {
        // ------------- tier 3: exactly 32 MiB, per-(batch,head) -------------
        bf16_t* h1    = (bf16_t*)(ws);                 // [4096,1536]  12.58 MB
        bf16_t* xb    = (bf16_t*)(ws + 12582912ull);   // [4096,512]    4.19 MB (dead after GEMM1)
        bf16_t* av_bh = (bf16_t*)(ws + 12582912ull);   //   reuse: [2048,512] bf16
        bf16_t* wsb   = (bf16_t*)(ws + 16777216ull);   // [1536,512]    1.57 MB
        bf16_t* wrb   = (bf16_t*)(ws + 18350080ull);   // [512,4096]    4.19 MB
        bf16_t* wmb_h = (bf16_t*)(ws + 22544384ull);   // [1536,1536]   4.72 MB
        bf16_t* qk_bh = (bf16_t*)(ws + 27262976ull);   // [2048,1024]   4.19 MB
        bf16_t* vT_bh = (bf16_t*)(ws + 31457280ull);   // [512,2048]    2.10 MB

        f32_to_bf16<<<dim3(2048), blk, 0, stream>>>(x,     xb,  2097152 / 4);
        f32_to_bf16<<<dim3( 768), blk, 0, stream>>>(W_sep, wsb,  786432 / 4);
        f32_to_bf16<<<dim3(2048), blk, 0, stream>>>(W_res, wrb,  2097152 / 4);

        gemm_bt<<<dim3(12, 32), blk, 0, stream>>>(xb, 512, wsb, 512, b_sep,
                                                  h1, nullptr, 0, 1536, 512,
                                                  nullptr, nullptr, 0);
        for (int h = 0; h < 8; ++h) {
            f32_to_bf16<<<dim3(2304), blk, 0, stream>>>(W_multi + (size_t)h * 1536 * 1536,
                                                        wmb_h, 2359296 / 4);
            for (int b = 0; b < 2; ++b) {
                gemm_bt<<<dim3(12, 16), blk, 0, stream>>>(h1 + (size_t)b * 2048 * 1536, 1536,
                        wmb_h, 1536, b_multi + h * 1536,
                        nullptr, nullptr, 0, 1536, 1536, qk_bh, vT_bh, 1);
                attn<<<dim3(16), dim3(512), 0, stream>>>(qk_bh, vT_bh, av_bh, 1, 1, 512, 0);
                gemm_bt<<<dim3(4, 16), blk, 0, stream>>>(av_bh, 512, wrb + h * 512, 4096,
                        (h == 0) ? b_res : nullptr, nullptr, out + (size_t)b * 2048 * 512,
                        (h == 0) ? 1 : 0, 512, 512, nullptr, nullptr, 0);
            }
        }
    }
}

// Round 7
// 991.127 us; speedup vs baseline: 2.7381x; 1.0479x over previous
//
#include <hip/hip_runtime.h>

// ============================================================================
// Attention_18923625906467 — MI355X (round 7)
//   out = ((x@Wsep^T)@Wmulti^T -> heads -> softmax(QK^T/sqrt(512))V) @ Wres^T
// B=2,S=2048,D=512,H=8.  f32 in/out; bf16 MFMA compute (2%-rel threshold).
//
// R6 profile: attn 627 µs, MfmaUtil 8.9%, HBM 1.7%, occ 24% — grid 256 = 1
// block/CU; the single barrier-coupled wave group serializes (23.5k cyc/step
// vs ~5k of pipe work). R7: 4-wave blocks (64 q-rows), grid 512 = 2
// independent blocks/CU -> cross-block overlap hides barrier/memory stalls.
// LDS/block: Vs 32 KB + P 4 KB = 36 KB (2 blocks/CU fits easily).
// ============================================================================

typedef __bf16 bf16_t;
typedef __bf16 bf16x4 __attribute__((ext_vector_type(4)));
typedef __bf16 bf16x8 __attribute__((ext_vector_type(8)));
typedef float  f32x4  __attribute__((ext_vector_type(4)));

#define BM 128
#define BN 128
#define BK 64
#define LDK 72   // GEMM LDS row stride (bf16): 144B = 9*16B aligned, 2-way banks

typedef const __attribute__((address_space(1))) void gvoid_t;
typedef __attribute__((address_space(3))) void svoid_t;

__device__ __forceinline__ void async_cp16(const bf16_t* g, bf16_t* l)
{
    __builtin_amdgcn_global_load_lds((gvoid_t*)g, (svoid_t*)l, 16, 0, 0);
}

// ---------------------------------------------------------------------------
__global__ void f32_to_bf16(const float* __restrict__ src, bf16_t* __restrict__ dst, int n4)
{
    const int i = blockIdx.x * 256 + threadIdx.x;
    if (i < n4) {
        const float4 v = ((const float4*)src)[i];
        bf16x4 o;
        o[0] = (bf16_t)v.x; o[1] = (bf16_t)v.y; o[2] = (bf16_t)v.z; o[3] = (bf16_t)v.w;
        ((bf16x4*)dst)[i] = o;
    }
}

// ---------------------------------------------------------------------------
// GEMM: D = A @ W^T + bias.  A:[M,lda], W:[N,ldw] row-major bf16, K inner.
//   C    != nullptr : write bf16 C[row*N+col]
//   Cacc != nullptr : f32 Cacc[row*N+col] = v (accFirst) or += v
//   qk   != nullptr : attention scatter (col = hh*1536 + off, row = bb*2048+ss):
//       off<1024 -> qk[((bb*hmul+hh)*2048+ss)*1024 + off]   (Q:0..511 K:512..1023)
//       else     -> vT[((bb*hmul+hh)*512+(off-1024))*2048 + ss]
// ---------------------------------------------------------------------------
__global__ __launch_bounds__(256, 2)
void gemm_bt(const bf16_t* __restrict__ A, int lda,
             const bf16_t* __restrict__ W, int ldw,
             const float* __restrict__ bias,
             bf16_t* __restrict__ C, float* __restrict__ Cacc, int accFirst,
             int N, int K,
             bf16_t* __restrict__ qk, bf16_t* __restrict__ vT, int hmul)
{
    __shared__ __align__(16) bf16_t As[BM * LDK];
    __shared__ __align__(16) bf16_t Ws[BN * LDK];

    const int tid  = threadIdx.x;
    const int wave = tid >> 6;
    const int lane = tid & 63;
    const int quad = lane >> 4;
    const int l16  = lane & 15;
    const int bm = blockIdx.y * BM;
    const int bn = blockIdx.x * BN;
    const int wm = (wave >> 1) * 64;
    const int wn = (wave & 1) * 64;

    f32x4 acc[4][4] = {};

    const int srow = tid >> 3;
    const int sseg = tid & 7;

    for (int k0 = 0; k0 < K; k0 += BK) {
        #pragma unroll
        for (int it = 0; it < 4; ++it) {
            const int row = it * 32 + srow;
            const int4 va = *(const int4*)(A + (size_t)(bm + row) * lda + k0 + sseg * 8);
            *(int4*)(As + row * LDK + sseg * 8) = va;
            const int4 vw = *(const int4*)(W + (size_t)(bn + row) * ldw + k0 + sseg * 8);
            *(int4*)(Ws + row * LDK + sseg * 8) = vw;
        }
        __syncthreads();
        #pragma unroll
        for (int kk = 0; kk < BK; kk += 32) {
            bf16x8 af[4], wf[4];
            #pragma unroll
            for (int i = 0; i < 4; ++i)
                af[i] = *(const bf16x8*)(As + (wm + i * 16 + l16) * LDK + kk + quad * 8);
            #pragma unroll
            for (int j = 0; j < 4; ++j)
                wf[j] = *(const bf16x8*)(Ws + (wn + j * 16 + l16) * LDK + kk + quad * 8);
            #pragma unroll
            for (int i = 0; i < 4; ++i)
                #pragma unroll
                for (int j = 0; j < 4; ++j)
                    acc[i][j] = __builtin_amdgcn_mfma_f32_16x16x32_bf16(af[i], wf[j], acc[i][j], 0, 0, 0);
        }
        __syncthreads();
    }

    #pragma unroll
    for (int j = 0; j < 4; ++j) {
        const int col = bn + wn + j * 16 + l16;
        const float bv = bias ? bias[col] : 0.f;
        #pragma unroll
        for (int i = 0; i < 4; ++i) {
            const int row0 = bm + wm + i * 16 + quad * 4;
            #pragma unroll
            for (int r = 0; r < 4; ++r) {
                const int row = row0 + r;
                const float v = acc[i][j][r] + bv;
                if (C)
                    C[(size_t)row * N + col] = (bf16_t)v;
                if (Cacc) {
                    const size_t idx = (size_t)row * N + col;
                    Cacc[idx] = accFirst ? v : (Cacc[idx] + v);
                }
                if (qk) {
                    const int hh  = col / 1536;
                    const int off = col - hh * 1536;
                    const int bb  = row >> 11;
                    const int ss  = row & 2047;
                    if (off < 1024)
                        qk[((size_t)((bb * hmul + hh) * 2048 + ss)) * 1024 + off] = (bf16_t)v;
                    else
                        vT[((size_t)((bb * hmul + hh) * 512 + (off - 1024))) * 2048 + ss] = (bf16_t)v;
                }
            }
        }
    }
}

// ---------------------------------------------------------------------------
// Flash attention, round-7 structure.
// Grid nPairs*32 blocks x 256 thr (4 waves, 64 q-rows/block, 16 per wave);
// 2 blocks/CU -> two independent barrier groups overlap each other's stalls.
// KT=32 keys/step, 64 steps. Per step:
//   QK from global K (L1-shared across waves) with preloaded Q regs
//   softmax -> P to wave-private LDS
//   __syncthreads (vmcnt drain -> V tile resident)
//   PV from LDS V tile
//   __syncthreads -> issue async V loads for next step
// ---------------------------------------------------------------------------
__global__ __launch_bounds__(256, 2)
void attn(const bf16_t* __restrict__ qk, const bf16_t* __restrict__ vT,
          bf16_t* __restrict__ aout, int nPairs, int nH,
          int out_stride, int coloff_per_head)
{
    __shared__ __align__(16) bf16_t Vs[512 * 32];       // 32 KB
    __shared__ __align__(16) bf16_t Plds[4][16 * 32];   //  4 KB

    const int tid  = threadIdx.x;
    const int wave = tid >> 6;
    const int lane = tid & 63;
    const int quad = lane >> 4;
    const int l16  = lane & 15;

    const int bid = blockIdx.x;
    const int p   = bid % nPairs;     // pair (b*nH + h)
    const int qt  = bid / nPairs;     // 0..31

    const int qbase = qt * 64 + wave * 16;
    const bf16_t* qp = qk + ((size_t)(p * 2048 + qbase)) * 1024;
    const bf16_t* kp = qk + ((size_t)(p * 2048)) * 1024 + 512;
    const bf16_t* vp = vT + (size_t)p * 512 * 2048;

    // V staging: 8 passes of 256 threads; idx = pp*256+tid; row = idx>>2,
    // seg = (idx&3)*8 elems; LDS byte = idx*16 (contiguous per wave).
    const int vrow = tid >> 2;
    const int vseg = (tid & 3) * 8;

    // ---- preload Q fragments (read exactly once) ----
    bf16x8 qreg[16];
    #pragma unroll
    for (int ks = 0; ks < 16; ++ks)
        qreg[ks] = *(const bf16x8*)(qp + (size_t)l16 * 1024 + ks * 32 + quad * 8);

    f32x4 o[32] = {};
    float m_i[4], l_i[4];
    #pragma unroll
    for (int r = 0; r < 4; ++r) { m_i[r] = -10000.f; l_i[r] = 0.f; }

    const float scale = 0.0441941738241592f;  // 1/sqrt(512)

    // ---- stage tile 0 (async) ----
    #pragma unroll
    for (int pp = 0; pp < 8; ++pp)
        async_cp16(vp + (size_t)(pp * 64 + vrow) * 2048 + vseg,
                   Vs + (size_t)(pp * 64 + vrow) * 32 + vseg);

    for (int kt = 0; kt < 64; ++kt) {
        const int key0 = kt * 32;

        // ---- S = Q K^T (16 q-rows x 32 keys per wave), K from global ----
        f32x4 s[2] = {};
        #pragma unroll
        for (int ks = 0; ks < 16; ++ks) {
            #pragma unroll
            for (int j = 0; j < 2; ++j) {
                const bf16x8 kf = *(const bf16x8*)(kp + (size_t)(key0 + j * 16 + l16) * 1024 + ks * 32 + quad * 8);
                s[j] = __builtin_amdgcn_mfma_f32_16x16x32_bf16(qreg[ks], kf, s[j], 0, 0, 0);
            }
        }
        s[0] *= scale; s[1] *= scale;

        // ---- online softmax; q-row r spans the quad's 16 lanes ----
        float alpha[4];
        #pragma unroll
        for (int r = 0; r < 4; ++r) {
            float v = fmaxf(s[0][r], s[1][r]);
            v = fmaxf(v, __shfl_xor(v, 1));
            v = fmaxf(v, __shfl_xor(v, 2));
            v = fmaxf(v, __shfl_xor(v, 4));
            v = fmaxf(v, __shfl_xor(v, 8));
            const float mn = fmaxf(m_i[r], v);
            alpha[r] = __expf(m_i[r] - mn);
            m_i[r] = mn;
        }
        #pragma unroll
        for (int r = 0; r < 4; ++r) {
            float t = 0.f;
            #pragma unroll
            for (int j = 0; j < 2; ++j) {
                const float pe = __expf(s[j][r] - m_i[r]);
                s[j][r] = pe;
                t += pe;
            }
            t += __shfl_xor(t, 1);
            t += __shfl_xor(t, 2);
            t += __shfl_xor(t, 4);
            t += __shfl_xor(t, 8);
            l_i[r] = l_i[r] * alpha[r] + t;
        }
        #pragma unroll
        for (int jj = 0; jj < 32; ++jj) {
            f32x4 a4 = o[jj];
            a4[0] *= alpha[0]; a4[1] *= alpha[1];
            a4[2] *= alpha[2]; a4[3] *= alpha[3];
            o[jj] = a4;
        }

        // ---- P: C-layout regs -> wave-private LDS (A-layout source) ----
        #pragma unroll
        for (int j = 0; j < 2; ++j)
            #pragma unroll
            for (int r = 0; r < 4; ++r)
                Plds[wave][(quad * 4 + r) * 32 + j * 16 + l16] = (bf16_t)s[j][r];

        __syncthreads();   // drains vmcnt -> V tile(kt) resident in Vs

        // ---- O += P V from LDS ----
        const bf16x8 pf = *(const bf16x8*)(&Plds[wave][l16 * 32 + quad * 8]);
        #pragma unroll
        for (int jj = 0; jj < 32; ++jj) {
            const bf16x8 vf = *(const bf16x8*)(&Vs[(jj * 16 + l16) * 32 + quad * 8]);
            o[jj] = __builtin_amdgcn_mfma_f32_16x16x32_bf16(pf, vf, o[jj], 0, 0, 0);
        }

        __syncthreads();   // all waves done reading Vs(kt)

        if (kt + 1 < 64) {
            const int nk = key0 + 32;
            #pragma unroll
            for (int pp = 0; pp < 8; ++pp)
                async_cp16(vp + (size_t)(pp * 64 + vrow) * 2048 + nk + vseg,
                           Vs + (size_t)(pp * 64 + vrow) * 32 + vseg);
        }
    }

    // ---- epilogue ----
    float inv[4];
    #pragma unroll
    for (int r = 0; r < 4; ++r) inv[r] = 1.f / l_i[r];
    const int b_out  = p / nH;
    const int coloff = (p % nH) * coloff_per_head;
    #pragma unroll
    for (int jj = 0; jj < 32; ++jj) {
        const int d = jj * 16 + l16;
        #pragma unroll
        for (int r = 0; r < 4; ++r) {
            const int row = b_out * 2048 + qbase + quad * 4 + r;
            aout[(size_t)row * out_stride + coloff + d] = (bf16_t)(o[jj][r] * inv[r]);
        }
    }
}

// ---------------------------------------------------------------------------
extern "C" void kernel_launch(void* const* d_in, const int* in_sizes, int n_in,
                              void* d_out, int out_size, void* d_ws, size_t ws_size,
                              hipStream_t stream)
{
    const float* x       = (const float*)d_in[0];  // [4096, 512]   f32
    const float* W_sep   = (const float*)d_in[1];  // [1536, 512]   f32
    const float* b_sep   = (const float*)d_in[2];  // [1536]        f32
    const float* W_multi = (const float*)d_in[3];  // [12288, 1536] f32
    const float* b_multi = (const float*)d_in[4];  // [12288]       f32
    const float* W_res   = (const float*)d_in[5];  // [512, 4096]   f32
    const float* b_res   = (const float*)d_in[6];  // [512]         f32
    float* out = (float*)d_out;                    // [4096, 512]   f32

    char* ws = (char*)d_ws;
    const dim3 blk(256);

    if (ws_size >= 160956416ull) {
        // ------------- tier 1: 161 MB, whole-problem dispatches -------------
        bf16_t* wmb = (bf16_t*)(ws);                   // [12288,1536] 37.75 MB
        bf16_t* av  = (bf16_t*)(ws);                   // [4096,4096]  33.55 MB (over wmb, dead)
        bf16_t* xb  = (bf16_t*)(ws +  37748736ull);    // [4096,512]    4.19 MB
        bf16_t* wsb = (bf16_t*)(ws +  41943040ull);    // [1536,512]    1.57 MB
        bf16_t* wrb = (bf16_t*)(ws +  43515904ull);    // [512,4096]    4.19 MB
        bf16_t* h1  = (bf16_t*)(ws +  47710208ull);    // [4096,1536]  12.58 MB
        bf16_t* qk  = (bf16_t*)(ws +  60293120ull);    // [2,8,2048,1024] 67.11 MB
        bf16_t* vT  = (bf16_t*)(ws + 127401984ull);    // [2,8,512,2048]  33.55 MB

        f32_to_bf16<<<dim3( 2048), blk, 0, stream>>>(x,       xb,  2097152 / 4);
        f32_to_bf16<<<dim3(  768), blk, 0, stream>>>(W_sep,   wsb,  786432 / 4);
        f32_to_bf16<<<dim3(18432), blk, 0, stream>>>(W_multi, wmb, 18874368 / 4);
        f32_to_bf16<<<dim3( 2048), blk, 0, stream>>>(W_res,   wrb,  2097152 / 4);

        gemm_bt<<<dim3(12, 32), blk, 0, stream>>>(xb, 512, wsb, 512, b_sep,
                                                  h1, nullptr, 0, 1536, 512,
                                                  nullptr, nullptr, 0);
        gemm_bt<<<dim3(96, 32), blk, 0, stream>>>(h1, 1536, wmb, 1536, b_multi,
                                                  nullptr, nullptr, 0, 12288, 1536,
                                                  qk, vT, 8);
        attn<<<dim3(512), blk, 0, stream>>>(qk, vT, av, 16, 8, 4096, 512);
        gemm_bt<<<dim3(4, 32), blk, 0, stream>>>(av, 4096, wrb, 4096, b_res,
                                                 nullptr, out, 1, 512, 4096,
                                                 nullptr, nullptr, 0);
    } else if (ws_size >= 39845888ull) {
        // ------------- tier 2: 39.8 MB, per-head streaming -------------
        bf16_t* h1    = (bf16_t*)(ws);                 // [4096,1536]  12.58 MB
        bf16_t* xb    = (bf16_t*)(ws + 12582912ull);   // [4096,512]    4.19 MB (dead after GEMM1)
        bf16_t* av_h  = (bf16_t*)(ws + 12582912ull);   //   reuse: [4096,512] bf16
        bf16_t* wsb   = (bf16_t*)(ws + 16777216ull);   // [1536,512]    1.57 MB
        bf16_t* wrb   = (bf16_t*)(ws + 18350080ull);   // [512,4096]    4.19 MB
        bf16_t* wmb_h = (bf16_t*)(ws + 22544384ull);   // [1536,1536]   4.72 MB
        bf16_t* qk_h  = (bf16_t*)(ws + 27262976ull);   // [2,2048,1024] 8.39 MB
        bf16_t* vT_h  = (bf16_t*)(ws + 35651584ull);   // [2,512,2048]  4.19 MB

        f32_to_bf16<<<dim3(2048), blk, 0, stream>>>(x,     xb,  2097152 / 4);
        f32_to_bf16<<<dim3( 768), blk, 0, stream>>>(W_sep, wsb,  786432 / 4);
        f32_to_bf16<<<dim3(2048), blk, 0, stream>>>(W_res, wrb,  2097152 / 4);

        gemm_bt<<<dim3(12, 32), blk, 0, stream>>>(xb, 512, wsb, 512, b_sep,
                                                  h1, nullptr, 0, 1536, 512,
                                                  nullptr, nullptr, 0);
        for (int h = 0; h < 8; ++h) {
            f32_to_bf16<<<dim3(2304), blk, 0, stream>>>(W_multi + (size_t)h * 1536 * 1536,
                                                        wmb_h, 2359296 / 4);
            gemm_bt<<<dim3(12, 32), blk, 0, stream>>>(h1, 1536, wmb_h, 1536,
                    b_multi + h * 1536, nullptr, nullptr, 0, 1536, 1536,
                    qk_h, vT_h, 1);
            attn<<<dim3(64), blk, 0, stream>>>(qk_h, vT_h, av_h, 2, 1, 512, 0);
            gemm_bt<<<dim3(4, 32), blk, 0, stream>>>(av_h, 512, wrb + h * 512, 4096,
                    (h == 0) ? b_res : nullptr, nullptr, out, (h == 0) ? 1 : 0,
                    512, 512, nullptr, nullptr, 0);
        }
    } else {
        // ------------- tier 3: exactly 32 MiB, per-(batch,head) -------------
        bf16_t* h1    = (bf16_t*)(ws);                 // [4096,1536]  12.58 MB
        bf16_t* xb    = (bf16_t*)(ws + 12582912ull);   // [4096,512]    4.19 MB (dead after GEMM1)
        bf16_t* av_bh = (bf16_t*)(ws + 12582912ull);   //   reuse: [2048,512] bf16
        bf16_t* wsb   = (bf16_t*)(ws + 16777216ull);   // [1536,512]    1.57 MB
        bf16_t* wrb   = (bf16_t*)(ws + 18350080ull);   // [512,4096]    4.19 MB
        bf16_t* wmb_h = (bf16_t*)(ws + 22544384ull);   // [1536,1536]   4.72 MB
        bf16_t* qk_bh = (bf16_t*)(ws + 27262976ull);   // [2048,1024]   4.19 MB
        bf16_t* vT_bh = (bf16_t*)(ws + 31457280ull);   // [512,2048]    2.10 MB

        f32_to_bf16<<<dim3(2048), blk, 0, stream>>>(x,     xb,  2097152 / 4);
        f32_to_bf16<<<dim3( 768), blk, 0, stream>>>(W_sep, wsb,  786432 / 4);
        f32_to_bf16<<<dim3(2048), blk, 0, stream>>>(W_res, wrb,  2097152 / 4);

        gemm_bt<<<dim3(12, 32), blk, 0, stream>>>(xb, 512, wsb, 512, b_sep,
                                                  h1, nullptr, 0, 1536, 512,
                                                  nullptr, nullptr, 0);
        for (int h = 0; h < 8; ++h) {
            f32_to_bf16<<<dim3(2304), blk, 0, stream>>>(W_multi + (size_t)h * 1536 * 1536,
                                                        wmb_h, 2359296 / 4);
            for (int b = 0; b < 2; ++b) {
                gemm_bt<<<dim3(12, 16), blk, 0, stream>>>(h1 + (size_t)b * 2048 * 1536, 1536,
                        wmb_h, 1536, b_multi + h * 1536,
                        nullptr, nullptr, 0, 1536, 1536, qk_bh, vT_bh, 1);
                attn<<<dim3(32), blk, 0, stream>>>(qk_bh, vT_bh, av_bh, 1, 1, 512, 0);
                gemm_bt<<<dim3(4, 16), blk, 0, stream>>>(av_bh, 512, wrb + h * 512, 4096,
                        (h == 0) ? b_res : nullptr, nullptr, out + (size_t)b * 2048 * 512,
                        (h == 0) ? 1 : 0, 512, 512, nullptr, nullptr, 0);
            }
        }
    }
}